// Round 12
// baseline (443.816 us; speedup 1.0000x reference)
//
#include <hip/hip_runtime.h>

typedef short bf16x8 __attribute__((ext_vector_type(8)));
typedef float f32x4 __attribute__((ext_vector_type(4)));

__device__ inline float bf2f(unsigned short s){ union{unsigned u; float f;} x; x.u=((unsigned)s)<<16; return x.f; }
__device__ inline unsigned short f2bf(float f){ union{float f; unsigned u;} x; x.f=f; unsigned r = x.u + 0x7fff + ((x.u>>16)&1u); return (unsigned short)(r>>16); }

// nt-store of a float4 via native ext-vector type (HIP_vector_type is rejected by the builtin)
__device__ inline void nt_store4(float4 v, float4* p){
    f32x4 t; t[0]=v.x; t[1]=v.y; t[2]=v.z; t[3]=v.w;
    __builtin_nontemporal_store(t, (f32x4*)p);
}

// async global->LDS, 16B per lane. ldsbase must be WAVE-UNIFORM; HW adds lane*16.
__device__ inline void gload16(const void* g, void* ldsbase){
    __builtin_amdgcn_global_load_lds((const __attribute__((address_space(1))) unsigned int*)g,
                                     (__attribute__((address_space(3))) unsigned int*)ldsbase, 16, 0, 0);
}

// ---------------- setup: hist | x->bf16 cvt (independent block ranges) ----------------
__global__ void k_hist_cvt(const int* __restrict__ dstA, int* __restrict__ cnt, int E, int histBlocks,
                           const float4* __restrict__ x4, ushort4* __restrict__ hb, int n4){
    int b = blockIdx.x;
    if(b < histBlocks){
        int e = b*256 + threadIdx.x;
        if(e < E) atomicAdd(&cnt[dstA[e]], 1);
    } else {
        int i = (b - histBlocks)*256 + threadIdx.x;
        if(i < n4){
            float4 v = x4[i];
            hb[i] = make_ushort4(f2bf(v.x), f2bf(v.y), f2bf(v.z), f2bf(v.w));
        }
    }
}

// scan1 also emits dinv = rsqrt(cnt+1)
__global__ void k_scan1(const int* __restrict__ cnt, int* __restrict__ tmp, int* __restrict__ bsum,
                        float* __restrict__ dinv, int n){
    __shared__ int s[1024];
    int i = blockIdx.x*1024 + threadIdx.x;
    int v = (i < n) ? cnt[i] : 0;
    if(i < n) dinv[i] = rsqrtf((float)(v + 1));
    s[threadIdx.x] = v; __syncthreads();
    for(int off=1; off<1024; off<<=1){
        int t = (threadIdx.x >= off) ? s[threadIdx.x-off] : 0;
        __syncthreads();
        s[threadIdx.x] += t;
        __syncthreads();
    }
    if(i < n) tmp[i] = s[threadIdx.x];
    if(threadIdx.x == 1023) bsum[blockIdx.x] = s[1023];
}

// scan3 (with in-block wave-scan of bsum, replaces serial k_scan2) | W transpose | pad zeroing
__global__ void k_scan3_misc(const int* __restrict__ tmp, const int* __restrict__ bsum, int* __restrict__ rowptr,
                             int n, int gN, int nbScan,
                             const float* __restrict__ W0, const float* __restrict__ W1, const float* __restrict__ W2,
                             unsigned short* __restrict__ Wt, float4* __restrict__ out4, int G){
    int b = blockIdx.x;
    if(b < gN){
        __shared__ int pfx[64];
        if(threadIdx.x < 64){
            int v = ((int)threadIdx.x < nbScan) ? bsum[threadIdx.x] : 0;
            #pragma unroll
            for(int off=1; off<64; off<<=1){
                int t = __shfl_up(v, off, 64);
                if((int)threadIdx.x >= off) v += t;
            }
            pfx[threadIdx.x] = v;   // inclusive prefix
        }
        __syncthreads();
        int i = b*256 + threadIdx.x;
        if(i < n){
            int blk = i >> 10;
            int p = (blk == 0) ? 0 : pfx[blk-1];   // exclusive prefix
            rowptr[i+1] = tmp[i] + p;
            if(i == 0) rowptr[0] = 0;
        }
    } else if(b < gN + 768){
        int idx = (b - gN)*256 + threadIdx.x;
        int l = idx >> 16, rem = idx & 65535;
        int k = rem >> 8, nn = rem & 255;
        const float* W = (l==0) ? W0 : ((l==1) ? W1 : W2);
        Wt[l*65536 + nn*256 + k] = f2bf(W[k*256 + nn]);
    } else {
        int i = (b - gN - 768)*256 + threadIdx.x;
        int rowsPad = 512 - G;
        int per = rowsPad * 192;
        int total = 100 * per;
        if(i < total){
            int g = i / per; int rem = i - g*per;
            int r = rem / 192, c = rem - r*192;
            nt_store4(make_float4(0.f,0.f,0.f,0.f), &out4[((size_t)(g*512 + G + r))*192 + c]);
        }
    }
}

// fill via count-down on cnt (slot order within a row is irrelevant); writes (col, weight) pairs
__global__ void k_fill(const int* __restrict__ srcA, const int* __restrict__ dstA,
                       const int* __restrict__ rowptr, int* __restrict__ cnt,
                       const float* __restrict__ dinv, int2* __restrict__ cew, int E){
    int e = blockIdx.x*256 + threadIdx.x;
    if(e < E){
        int d = dstA[e], s = srcA[e];
        int slot = atomicSub(&cnt[d], 1) - 1;
        int j = rowptr[d] + slot;
        cew[j] = make_int2(s, __float_as_int(dinv[s]));
    }
}

// ---------------- GEMM: y[N,256] = hb[N,256] @ W[256,256]  (bf16 in, bf16 out) ----------------
// 128x256 tile (full output width per block -> A staged once).
// staging: global_load_lds width=16, linear LDS dest, pre-swizzled global source;
// reads use byte ^ ((row&7)<<4).
__global__ __launch_bounds__(256) void k_gemm(const uint4* __restrict__ A4,
                                              const uint4* __restrict__ B4,
                                              unsigned short* __restrict__ Y, int M){
    __shared__ uint4 smA[1024];   // 128 rows x 64 bf16 (16KB)
    __shared__ uint4 smB[2048];   // 256 rows x 64 bf16 (32KB)
    const int tid  = threadIdx.x;
    const int lane = tid & 63;
    const int w    = tid >> 6;
    const int wr   = w >> 1, wc = w & 1;      // wave covers 64 rows x 128 cols
    const int r15  = lane & 15, hi = lane >> 4;
    const int rsub = lane >> 3, ch = lane & 7;
    const int rowBase = blockIdx.x * 128;

    f32x4 acc[4][8] = {};
    char* pA = (char*)smA;
    char* pB = (char*)smB;

    for(int kt=0; kt<4; ++kt){
        const int kc0 = kt*8;
        // stage A: 128 rows
        #pragma unroll
        for(int i=0;i<4;++i){
            int row  = i*32 + w*8 + rsub;
            int gch  = kc0 + (ch ^ (row & 7));
            char* la = pA + i*4096 + w*1024;
            int grow = rowBase + row;
            if(grow < M) gload16(&A4[(size_t)grow*32 + gch], la);
        }
        // stage B: 256 rows
        #pragma unroll
        for(int i=0;i<8;++i){
            int row  = i*32 + w*8 + rsub;
            int gch  = kc0 + (ch ^ (row & 7));
            char* lb = pB + i*4096 + w*1024;
            gload16(&B4[(size_t)row*32 + gch], lb);
        }
        __syncthreads();
        #pragma unroll
        for(int kk=0; kk<2; ++kk){
            const int kbyte = kk*64 + hi*16;
            bf16x8 fa[4];
            #pragma unroll
            for(int m=0;m<4;++m){
                int lrow = wr*64 + m*16 + r15;
                fa[m] = *(const bf16x8*)(pA + (lrow<<7) + (kbyte ^ ((lrow&7)<<4)));
            }
            #pragma unroll
            for(int nn=0;nn<8;++nn){
                int lcol = wc*128 + nn*16 + r15;
                bf16x8 fb = *(const bf16x8*)(pB + (lcol<<7) + (kbyte ^ ((lcol&7)<<4)));
                #pragma unroll
                for(int m=0;m<4;++m)
                    acc[m][nn] = __builtin_amdgcn_mfma_f32_16x16x32_bf16(fa[m], fb, acc[m][nn], 0,0,0);
            }
        }
        __syncthreads();
    }
    #pragma unroll
    for(int m=0;m<4;++m){
        int growb = rowBase + wr*64 + m*16 + hi*4;
        #pragma unroll
        for(int nn=0;nn<8;++nn){
            int gcol = wc*128 + nn*16 + r15;
            #pragma unroll
            for(int r=0;r<4;++r){
                int grow = growb + r;
                if(grow < M) Y[(size_t)grow*256 + gcol] = f2bf(acc[m][nn][r]);
            }
        }
    }
}

// ---------------- aggregation + fused BN partial stats; split-lane dual-row gathers (4 dual-streams) ----------------
// lanes 0-31 gather even edges (16B/lane), lanes 32-63 odd edges; __shfl(lane^32) combines.
__global__ __launch_bounds__(256) void k_aggregate(const uint4* __restrict__ yb4,
                                                   const int* __restrict__ rowptr,
                                                   const int2* __restrict__ cew,
                                                   const float* __restrict__ dinv,
                                                   uint4* __restrict__ zb4,
                                                   float* __restrict__ part, int n){
    int lane = threadIdx.x & 63;
    int w    = threadIdx.x >> 6;
    int half = lane >> 5;          // 0: even edges, 1: odd edges
    int c    = lane & 31;          // 16B chunk index within a row
    float s[8] = {0,0,0,0,0,0,0,0};
    float q[8] = {0,0,0,0,0,0,0,0};

    for(int wid = blockIdx.x*4 + w; wid < n; wid += 2048*4){
        float di = dinv[wid];
        float acc[4][8];
        // self-loop: only half 0 accumulates it (half 1 gets weight 0)
        {
            uint4 d = yb4[(size_t)wid*32 + c];
            float ws = half ? 0.f : di;
            const unsigned short* p = (const unsigned short*)&d;
            #pragma unroll
            for(int k=0;k<8;++k) acc[0][k] = ws*bf2f(p[k]);
            #pragma unroll
            for(int k=0;k<8;++k){ acc[1][k]=0.f; acc[2][k]=0.f; acc[3][k]=0.f; }
        }
        int j = rowptr[wid], end = rowptr[wid+1];
        for(; j+7 < end; j += 8){
            #pragma unroll
            for(int u=0;u<4;++u){
                int2 e = cew[j + 2*u + half];
                float wt = __int_as_float(e.y);
                uint4 d = yb4[(size_t)e.x*32 + c];
                const unsigned short* p = (const unsigned short*)&d;
                #pragma unroll
                for(int k=0;k<8;++k) acc[u][k] += wt*bf2f(p[k]);
            }
        }
        for(; j+1 < end; j += 2){
            int2 e = cew[j + half];
            float wt = __int_as_float(e.y);
            uint4 d = yb4[(size_t)e.x*32 + c];
            const unsigned short* p = (const unsigned short*)&d;
            #pragma unroll
            for(int k=0;k<8;++k) acc[0][k] += wt*bf2f(p[k]);
        }
        if(j < end){
            int2 e = cew[j];
            float wt = half ? 0.f : __int_as_float(e.y);
            uint4 d = yb4[(size_t)e.x*32 + c];
            const unsigned short* p = (const unsigned short*)&d;
            #pragma unroll
            for(int k=0;k<8;++k) acc[0][k] += wt*bf2f(p[k]);
        }
        // merge 4 streams, then merge the two half-waves
        float o[8];
        #pragma unroll
        for(int k=0;k<8;++k){
            float v = (acc[0][k]+acc[1][k]) + (acc[2][k]+acc[3][k]);
            v += __shfl(v, lane ^ 32);
            o[k] = di * v;
        }
        if(half == 0){
            uint4 z;
            z.x = (unsigned)f2bf(o[0]) | ((unsigned)f2bf(o[1])<<16);
            z.y = (unsigned)f2bf(o[2]) | ((unsigned)f2bf(o[3])<<16);
            z.z = (unsigned)f2bf(o[4]) | ((unsigned)f2bf(o[5])<<16);
            z.w = (unsigned)f2bf(o[6]) | ((unsigned)f2bf(o[7])<<16);
            zb4[(size_t)wid*32 + c] = z;
            #pragma unroll
            for(int k=0;k<8;++k){ s[k] += o[k]; q[k] += o[k]*o[k]; }
        }
    }
    __shared__ float red[4][32][16];
    if(half == 0){
        #pragma unroll
        for(int k=0;k<8;++k){ red[w][c][k] = s[k]; red[w][c][8+k] = q[k]; }
    }
    __syncthreads();
    int t = threadIdx.x;  // feature t: chunk t>>3, elem t&7
    float vs = red[0][t>>3][t&7] + red[1][t>>3][t&7] + red[2][t>>3][t&7] + red[3][t>>3][t&7];
    float vq = red[0][t>>3][8+(t&7)] + red[1][t>>3][8+(t&7)] + red[2][t>>3][8+(t&7)] + red[3][t>>3][8+(t&7)];
    part[(size_t)blockIdx.x*512 + t]       = vs;
    part[(size_t)blockIdx.x*512 + 256 + t] = vq;
}

// reduce 2048 block-partials -> 64 ; LAST block also reduces 64 -> ab (folds old red2)
__global__ __launch_bounds__(256) void k_red(const float* __restrict__ part, float* __restrict__ part2,
                                             const float* __restrict__ gamma, const float* __restrict__ beta,
                                             float* __restrict__ ab, float invN, int* __restrict__ ctr){
    int c = threadIdx.x;
    int b = blockIdx.x;   // 0..63
    float s = 0.f, q = 0.f;
    for(int j = b*32; j < b*32 + 32; ++j){
        s += part[(size_t)j*512 + c];
        q += part[(size_t)j*512 + 256 + c];
    }
    part2[(size_t)b*512 + c]       = s;
    part2[(size_t)b*512 + 256 + c] = q;

    __threadfence();              // release our part2 stores (device scope)
    __syncthreads();
    __shared__ int lastFlag;
    if(threadIdx.x == 0){
        int old = atomicAdd(ctr, 1);
        lastFlag = (old == 63);
    }
    __syncthreads();
    if(lastFlag){
        __threadfence();          // acquire all blocks' part2 stores
        float ss = 0.f, qq = 0.f;
        for(int j=0;j<64;++j){
            ss += part2[(size_t)j*512 + c];
            qq += part2[(size_t)j*512 + 256 + c];
        }
        float mu  = ss*invN;
        float var = qq*invN - mu*mu;
        float A   = gamma[c]*rsqrtf(var + 1e-5f);
        ab[c]       = A;
        ab[256 + c] = beta[c] - mu*A;
    }
}

// ---------------- BN affine + ReLU + next-layer bf16 + dense-batch output write (nt) ----------------
__global__ __launch_bounds__(256) void k_bnrelu(const ushort4* __restrict__ zb, const float* __restrict__ ab,
                                                ushort4* __restrict__ hb_out, float4* __restrict__ out4,
                                                int layer, int n4, int G){
    int idx = blockIdx.x*256 + threadIdx.x;
    if(idx >= n4) return;
    int node = idx >> 6, q = idx & 63;
    ushort4 v = zb[idx];
    float4 A  = ((const float4*)ab)[q];
    float4 Bv = ((const float4*)(ab + 256))[q];
    float4 r;
    r.x = fmaxf(fmaf(bf2f(v.x), A.x, Bv.x), 0.f);
    r.y = fmaxf(fmaf(bf2f(v.y), A.y, Bv.y), 0.f);
    r.z = fmaxf(fmaf(bf2f(v.z), A.z, Bv.z), 0.f);
    r.w = fmaxf(fmaf(bf2f(v.w), A.w, Bv.w), 0.f);
    if(hb_out) hb_out[idx] = make_ushort4(f2bf(r.x), f2bf(r.y), f2bf(r.z), f2bf(r.w));
    int g2 = node / G;
    int p  = node - g2*G;
    nt_store4(r, &out4[((size_t)(g2*512 + p))*192 + layer*64 + q]);
}

extern "C" void kernel_launch(void* const* d_in, const int* in_sizes, int n_in,
                              void* d_out, int out_size, void* d_ws, size_t ws_size,
                              hipStream_t stream){
    const int F = 256;
    const int N = in_sizes[0] / F;      // 50000
    const int E = in_sizes[1] / 2;      // 800000
    const int Bg = 100;
    const int G = N / Bg;               // 500

    const float* x  = (const float*)d_in[0];
    const int*   ei = (const int*)d_in[1];
    const float* Wp[3]  = {(const float*)d_in[4],  (const float*)d_in[8],  (const float*)d_in[12]};
    const float* gam[3] = {(const float*)d_in[6],  (const float*)d_in[10], (const float*)d_in[14]};
    const float* bet[3] = {(const float*)d_in[7],  (const float*)d_in[11], (const float*)d_in[15]};
    float* out = (float*)d_out;

    char* wp = (char*)d_ws;
    auto alloc = [&](size_t b)->char*{ char* p = wp; wp += ((b + 255)/256)*256; return p; };
    int*   cnt    = (int*)  alloc((size_t)N*4);
    int*   ctr    = (int*)  alloc(256);                  // 3 layer counters (zeroed with cnt)
    int*   rowptr = (int*)  alloc((size_t)(N+1)*4);
    int*   tmp    = (int*)  alloc((size_t)N*4);
    int*   bsum   = (int*)  alloc(256*4);
    int2*  cew    = (int2*) alloc((size_t)E*8);
    float* dinv   = (float*)alloc((size_t)N*4);
    float* part   = (float*)alloc((size_t)2048*512*4);   // 4 MB
    float* part2  = (float*)alloc((size_t)64*512*4);     // 128 KB
    float* ab     = (float*)alloc(3*512*4);              // per-layer affine (A,B)
    unsigned short* Wt  = (unsigned short*)alloc(3*65536*2);
    unsigned short* hbA = (unsigned short*)alloc((size_t)N*256*2);
    unsigned short* hbB = (unsigned short*)alloc((size_t)N*256*2);
    unsigned short* ybf = (unsigned short*)alloc((size_t)N*256*2);
    unsigned short* zb  = (unsigned short*)alloc((size_t)N*256*2);

    // cnt region is rounded to 256B; ctr sits immediately after -> one memset covers both
    size_t cntRound = (((size_t)N*4 + 255)/256)*256;
    (void)hipMemsetAsync(cnt, 0, cntRound + 256, stream);

    const int* srcA = ei;
    const int* dstA = ei + E;
    int gE = (E+255)/256, gN = (N+255)/256;
    int n4 = N*64;
    int nbCvt = (n4+255)/256;
    k_hist_cvt<<<gE + nbCvt, 256, 0, stream>>>(dstA, cnt, E, gE, (const float4*)x, (ushort4*)hbA, n4);
    int nb = (N+1023)/1024;
    k_scan1<<<nb,1024,0,stream>>>(cnt, tmp, bsum, dinv, N);
    int padBlocks = (Bg*(512-G)*192 + 255)/256;
    k_scan3_misc<<<gN + 768 + padBlocks, 256, 0, stream>>>(tmp, bsum, rowptr, N, gN, nb,
                                                           Wp[0], Wp[1], Wp[2], Wt, (float4*)out, G);
    k_fill<<<gE,256,0,stream>>>(srcA, dstA, rowptr, cnt, dinv, cew, E);

    unsigned short* hin  = hbA;
    unsigned short* hout = hbB;
    int ggrid = (N+127)/128;
    float invN = 1.0f / (float)N;
    for(int l=0; l<3; ++l){
        float* lab = ab + l*512;
        k_gemm<<<ggrid,256,0,stream>>>((const uint4*)hin, (const uint4*)(Wt + (size_t)l*65536), ybf, N);
        k_aggregate<<<2048,256,0,stream>>>((const uint4*)ybf, rowptr, cew, dinv, (uint4*)zb, part, N);
        k_red<<<64,256,0,stream>>>(part, part2, gam[l], bet[l], lab, invN, ctr + l);
        k_bnrelu<<<(n4+255)/256,256,0,stream>>>((const ushort4*)zb, lab,
                                                (l<2) ? (ushort4*)hout : (ushort4*)nullptr,
                                                (float4*)out, l, n4, G);
        unsigned short* t = hin; hin = hout; hout = t;
    }
}

// Round 13
// 438.022 us; speedup vs baseline: 1.0132x; 1.0132x over previous
//
#include <hip/hip_runtime.h>

typedef short bf16x8 __attribute__((ext_vector_type(8)));
typedef float f32x4 __attribute__((ext_vector_type(4)));

__device__ inline float bf2f(unsigned short s){ union{unsigned u; float f;} x; x.u=((unsigned)s)<<16; return x.f; }
__device__ inline unsigned short f2bf(float f){ union{float f; unsigned u;} x; x.f=f; unsigned r = x.u + 0x7fff + ((x.u>>16)&1u); return (unsigned short)(r>>16); }

// nt-store of a float4 via native ext-vector type (HIP_vector_type is rejected by the builtin)
__device__ inline void nt_store4(float4 v, float4* p){
    f32x4 t; t[0]=v.x; t[1]=v.y; t[2]=v.z; t[3]=v.w;
    __builtin_nontemporal_store(t, (f32x4*)p);
}

// async global->LDS, 16B per lane. ldsbase must be WAVE-UNIFORM; HW adds lane*16.
__device__ inline void gload16(const void* g, void* ldsbase){
    __builtin_amdgcn_global_load_lds((const __attribute__((address_space(1))) unsigned int*)g,
                                     (__attribute__((address_space(3))) unsigned int*)ldsbase, 16, 0, 0);
}

// ---------------- setup: hist | x->bf16 cvt (independent block ranges) ----------------
__global__ void k_hist_cvt(const int* __restrict__ dstA, int* __restrict__ cnt, int E, int histBlocks,
                           const float4* __restrict__ x4, ushort4* __restrict__ hb, int n4){
    int b = blockIdx.x;
    if(b < histBlocks){
        int e = b*256 + threadIdx.x;
        if(e < E) atomicAdd(&cnt[dstA[e]], 1);
    } else {
        int i = (b - histBlocks)*256 + threadIdx.x;
        if(i < n4){
            float4 v = x4[i];
            hb[i] = make_ushort4(f2bf(v.x), f2bf(v.y), f2bf(v.z), f2bf(v.w));
        }
    }
}

// scan1 also emits dinv = rsqrt(cnt+1)
__global__ void k_scan1(const int* __restrict__ cnt, int* __restrict__ tmp, int* __restrict__ bsum,
                        float* __restrict__ dinv, int n){
    __shared__ int s[1024];
    int i = blockIdx.x*1024 + threadIdx.x;
    int v = (i < n) ? cnt[i] : 0;
    if(i < n) dinv[i] = rsqrtf((float)(v + 1));
    s[threadIdx.x] = v; __syncthreads();
    for(int off=1; off<1024; off<<=1){
        int t = (threadIdx.x >= off) ? s[threadIdx.x-off] : 0;
        __syncthreads();
        s[threadIdx.x] += t;
        __syncthreads();
    }
    if(i < n) tmp[i] = s[threadIdx.x];
    if(threadIdx.x == 1023) bsum[blockIdx.x] = s[1023];
}

// scan3 (with in-block wave-scan of bsum) | W transpose | pad zeroing
__global__ void k_scan3_misc(const int* __restrict__ tmp, const int* __restrict__ bsum, int* __restrict__ rowptr,
                             int n, int gN, int nbScan,
                             const float* __restrict__ W0, const float* __restrict__ W1, const float* __restrict__ W2,
                             unsigned short* __restrict__ Wt, float4* __restrict__ out4, int G){
    int b = blockIdx.x;
    if(b < gN){
        __shared__ int pfx[64];
        if(threadIdx.x < 64){
            int v = ((int)threadIdx.x < nbScan) ? bsum[threadIdx.x] : 0;
            #pragma unroll
            for(int off=1; off<64; off<<=1){
                int t = __shfl_up(v, off, 64);
                if((int)threadIdx.x >= off) v += t;
            }
            pfx[threadIdx.x] = v;   // inclusive prefix
        }
        __syncthreads();
        int i = b*256 + threadIdx.x;
        if(i < n){
            int blk = i >> 10;
            int p = (blk == 0) ? 0 : pfx[blk-1];   // exclusive prefix
            rowptr[i+1] = tmp[i] + p;
            if(i == 0) rowptr[0] = 0;
        }
    } else if(b < gN + 768){
        int idx = (b - gN)*256 + threadIdx.x;
        int l = idx >> 16, rem = idx & 65535;
        int k = rem >> 8, nn = rem & 255;
        const float* W = (l==0) ? W0 : ((l==1) ? W1 : W2);
        Wt[l*65536 + nn*256 + k] = f2bf(W[k*256 + nn]);
    } else {
        int i = (b - gN - 768)*256 + threadIdx.x;
        int rowsPad = 512 - G;
        int per = rowsPad * 192;
        int total = 100 * per;
        if(i < total){
            int g = i / per; int rem = i - g*per;
            int r = rem / 192, c = rem - r*192;
            nt_store4(make_float4(0.f,0.f,0.f,0.f), &out4[((size_t)(g*512 + G + r))*192 + c]);
        }
    }
}

// fill via count-down on cnt (slot order within a row is irrelevant); writes (col, weight) pairs
__global__ void k_fill(const int* __restrict__ srcA, const int* __restrict__ dstA,
                       const int* __restrict__ rowptr, int* __restrict__ cnt,
                       const float* __restrict__ dinv, int2* __restrict__ cew, int E){
    int e = blockIdx.x*256 + threadIdx.x;
    if(e < E){
        int d = dstA[e], s = srcA[e];
        int slot = atomicSub(&cnt[d], 1) - 1;
        int j = rowptr[d] + slot;
        cew[j] = make_int2(s, __float_as_int(dinv[s]));
    }
}

// ---------------- GEMM: y[N,256] = hb[N,256] @ W[256,256]  (bf16 in, bf16 out) ----------------
// 128x128 tile, grid (ceil(N/128), 2) — round-11 proven version.
__global__ __launch_bounds__(256) void k_gemm(const uint4* __restrict__ A4,
                                              const uint4* __restrict__ B4,
                                              unsigned short* __restrict__ Y, int M){
    __shared__ uint4 smA[1024];   // 128 rows x 64 bf16
    __shared__ uint4 smB[1024];
    const int tid  = threadIdx.x;
    const int lane = tid & 63;
    const int w    = tid >> 6;
    const int wr   = w >> 1, wc = w & 1;
    const int r15  = lane & 15, hi = lane >> 4;
    const int rsub = lane >> 3, ch = lane & 7;
    const int rowBase = blockIdx.x * 128;
    const int colBase = blockIdx.y * 128;

    f32x4 acc[4][4] = {};
    char* pA = (char*)smA;
    char* pB = (char*)smB;

    for(int kt=0; kt<4; ++kt){
        const int kc0 = kt*8;
        #pragma unroll
        for(int i=0;i<4;++i){
            int row  = i*32 + w*8 + rsub;           // LDS row this lane covers
            int gch  = kc0 + (ch ^ (row & 7));      // pre-swizzled source chunk
            char* la = pA + i*4096 + w*1024;        // wave-uniform base; HW adds lane*16
            char* lb = pB + i*4096 + w*1024;
            int grow = rowBase + row;
            if(grow < M) gload16(&A4[(size_t)grow*32 + gch], la);
            gload16(&B4[(size_t)(colBase + row)*32 + gch], lb);
        }
        __syncthreads();
        #pragma unroll
        for(int kk=0; kk<2; ++kk){
            const int kbyte = kk*64 + hi*16;
            bf16x8 fa[4], fb[4];
            #pragma unroll
            for(int m=0;m<4;++m){
                int lrow = wr*64 + m*16 + r15;
                fa[m] = *(const bf16x8*)(pA + (lrow<<7) + (kbyte ^ ((lrow&7)<<4)));
            }
            #pragma unroll
            for(int nn=0;nn<4;++nn){
                int lcol = wc*64 + nn*16 + r15;
                fb[nn] = *(const bf16x8*)(pB + (lcol<<7) + (kbyte ^ ((lcol&7)<<4)));
            }
            #pragma unroll
            for(int m=0;m<4;++m)
                #pragma unroll
                for(int nn=0;nn<4;++nn)
                    acc[m][nn] = __builtin_amdgcn_mfma_f32_16x16x32_bf16(fa[m], fb[nn], acc[m][nn], 0,0,0);
        }
        __syncthreads();
    }
    #pragma unroll
    for(int m=0;m<4;++m){
        int growb = rowBase + wr*64 + m*16 + hi*4;
        #pragma unroll
        for(int nn=0;nn<4;++nn){
            int gcol = colBase + wc*64 + nn*16 + r15;
            #pragma unroll
            for(int r=0;r<4;++r){
                int grow = growb + r;
                if(grow < M) Y[(size_t)grow*256 + gcol] = f2bf(acc[m][nn][r]);
            }
        }
    }
}

// ---------------- aggregation + fused BN partial stats; split-lane dual-row gathers (4 dual-streams) ----------------
// lanes 0-31 gather even edges (16B/lane), lanes 32-63 odd edges; __shfl(lane^32) combines.
__global__ __launch_bounds__(256) void k_aggregate(const uint4* __restrict__ yb4,
                                                   const int* __restrict__ rowptr,
                                                   const int2* __restrict__ cew,
                                                   const float* __restrict__ dinv,
                                                   uint4* __restrict__ zb4,
                                                   float* __restrict__ part, int n){
    int lane = threadIdx.x & 63;
    int w    = threadIdx.x >> 6;
    int half = lane >> 5;          // 0: even edges, 1: odd edges
    int c    = lane & 31;          // 16B chunk index within a row
    float s[8] = {0,0,0,0,0,0,0,0};
    float q[8] = {0,0,0,0,0,0,0,0};

    for(int wid = blockIdx.x*4 + w; wid < n; wid += 2048*4){
        float di = dinv[wid];
        float acc[4][8];
        // self-loop: only half 0 accumulates it (half 1 gets weight 0)
        {
            uint4 d = yb4[(size_t)wid*32 + c];
            float ws = half ? 0.f : di;
            const unsigned short* p = (const unsigned short*)&d;
            #pragma unroll
            for(int k=0;k<8;++k) acc[0][k] = ws*bf2f(p[k]);
            #pragma unroll
            for(int k=0;k<8;++k){ acc[1][k]=0.f; acc[2][k]=0.f; acc[3][k]=0.f; }
        }
        int j = rowptr[wid], end = rowptr[wid+1];
        for(; j+7 < end; j += 8){
            #pragma unroll
            for(int u=0;u<4;++u){
                int2 e = cew[j + 2*u + half];
                float wt = __int_as_float(e.y);
                uint4 d = yb4[(size_t)e.x*32 + c];
                const unsigned short* p = (const unsigned short*)&d;
                #pragma unroll
                for(int k=0;k<8;++k) acc[u][k] += wt*bf2f(p[k]);
            }
        }
        for(; j+1 < end; j += 2){
            int2 e = cew[j + half];
            float wt = __int_as_float(e.y);
            uint4 d = yb4[(size_t)e.x*32 + c];
            const unsigned short* p = (const unsigned short*)&d;
            #pragma unroll
            for(int k=0;k<8;++k) acc[0][k] += wt*bf2f(p[k]);
        }
        if(j < end){
            int2 e = cew[j];
            float wt = half ? 0.f : __int_as_float(e.y);
            uint4 d = yb4[(size_t)e.x*32 + c];
            const unsigned short* p = (const unsigned short*)&d;
            #pragma unroll
            for(int k=0;k<8;++k) acc[0][k] += wt*bf2f(p[k]);
        }
        // merge 4 streams, then merge the two half-waves
        float o[8];
        #pragma unroll
        for(int k=0;k<8;++k){
            float v = (acc[0][k]+acc[1][k]) + (acc[2][k]+acc[3][k]);
            v += __shfl(v, lane ^ 32);
            o[k] = di * v;
        }
        if(half == 0){
            uint4 z;
            z.x = (unsigned)f2bf(o[0]) | ((unsigned)f2bf(o[1])<<16);
            z.y = (unsigned)f2bf(o[2]) | ((unsigned)f2bf(o[3])<<16);
            z.z = (unsigned)f2bf(o[4]) | ((unsigned)f2bf(o[5])<<16);
            z.w = (unsigned)f2bf(o[6]) | ((unsigned)f2bf(o[7])<<16);
            zb4[(size_t)wid*32 + c] = z;
            #pragma unroll
            for(int k=0;k<8;++k){ s[k] += o[k]; q[k] += o[k]*o[k]; }
        }
    }
    __shared__ float red[4][32][16];
    if(half == 0){
        #pragma unroll
        for(int k=0;k<8;++k){ red[w][c][k] = s[k]; red[w][c][8+k] = q[k]; }
    }
    __syncthreads();
    int t = threadIdx.x;  // feature t: chunk t>>3, elem t&7
    float vs = red[0][t>>3][t&7] + red[1][t>>3][t&7] + red[2][t>>3][t&7] + red[3][t>>3][t&7];
    float vq = red[0][t>>3][8+(t&7)] + red[1][t>>3][8+(t&7)] + red[2][t>>3][8+(t&7)] + red[3][t>>3][8+(t&7)];
    part[(size_t)blockIdx.x*512 + t]       = vs;
    part[(size_t)blockIdx.x*512 + 256 + t] = vq;
}

// reduce 2048 block-partials -> 64 ; LAST block also reduces 64 -> ab (folds old red2)
__global__ __launch_bounds__(256) void k_red(const float* __restrict__ part, float* __restrict__ part2,
                                             const float* __restrict__ gamma, const float* __restrict__ beta,
                                             float* __restrict__ ab, float invN, int* __restrict__ ctr){
    int c = threadIdx.x;
    int b = blockIdx.x;   // 0..63
    float s = 0.f, q = 0.f;
    for(int j = b*32; j < b*32 + 32; ++j){
        s += part[(size_t)j*512 + c];
        q += part[(size_t)j*512 + 256 + c];
    }
    part2[(size_t)b*512 + c]       = s;
    part2[(size_t)b*512 + 256 + c] = q;

    __threadfence();              // release our part2 stores (device scope)
    __syncthreads();
    __shared__ int lastFlag;
    if(threadIdx.x == 0){
        int old = atomicAdd(ctr, 1);
        lastFlag = (old == 63);
    }
    __syncthreads();
    if(lastFlag){
        __threadfence();          // acquire all blocks' part2 stores
        float ss = 0.f, qq = 0.f;
        for(int j=0;j<64;++j){
            ss += part2[(size_t)j*512 + c];
            qq += part2[(size_t)j*512 + 256 + c];
        }
        float mu  = ss*invN;
        float var = qq*invN - mu*mu;
        float A   = gamma[c]*rsqrtf(var + 1e-5f);
        ab[c]       = A;
        ab[256 + c] = beta[c] - mu*A;
    }
}

// ---------------- BN affine + ReLU + next-layer bf16 + dense-batch output write (nt) ----------------
__global__ __launch_bounds__(256) void k_bnrelu(const ushort4* __restrict__ zb, const float* __restrict__ ab,
                                                ushort4* __restrict__ hb_out, float4* __restrict__ out4,
                                                int layer, int n4, int G){
    int idx = blockIdx.x*256 + threadIdx.x;
    if(idx >= n4) return;
    int node = idx >> 6, q = idx & 63;
    ushort4 v = zb[idx];
    float4 A  = ((const float4*)ab)[q];
    float4 Bv = ((const float4*)(ab + 256))[q];
    float4 r;
    r.x = fmaxf(fmaf(bf2f(v.x), A.x, Bv.x), 0.f);
    r.y = fmaxf(fmaf(bf2f(v.y), A.y, Bv.y), 0.f);
    r.z = fmaxf(fmaf(bf2f(v.z), A.z, Bv.z), 0.f);
    r.w = fmaxf(fmaf(bf2f(v.w), A.w, Bv.w), 0.f);
    if(hb_out) hb_out[idx] = make_ushort4(f2bf(r.x), f2bf(r.y), f2bf(r.z), f2bf(r.w));
    int g2 = node / G;
    int p  = node - g2*G;
    nt_store4(r, &out4[((size_t)(g2*512 + p))*192 + layer*64 + q]);
}

extern "C" void kernel_launch(void* const* d_in, const int* in_sizes, int n_in,
                              void* d_out, int out_size, void* d_ws, size_t ws_size,
                              hipStream_t stream){
    const int F = 256;
    const int N = in_sizes[0] / F;      // 50000
    const int E = in_sizes[1] / 2;      // 800000
    const int Bg = 100;
    const int G = N / Bg;               // 500

    const float* x  = (const float*)d_in[0];
    const int*   ei = (const int*)d_in[1];
    const float* Wp[3]  = {(const float*)d_in[4],  (const float*)d_in[8],  (const float*)d_in[12]};
    const float* gam[3] = {(const float*)d_in[6],  (const float*)d_in[10], (const float*)d_in[14]};
    const float* bet[3] = {(const float*)d_in[7],  (const float*)d_in[11], (const float*)d_in[15]};
    float* out = (float*)d_out;

    char* wp = (char*)d_ws;
    auto alloc = [&](size_t b)->char*{ char* p = wp; wp += ((b + 255)/256)*256; return p; };
    int*   cnt    = (int*)  alloc((size_t)N*4);
    int*   ctr    = (int*)  alloc(256);                  // 3 layer counters (zeroed with cnt)
    int*   rowptr = (int*)  alloc((size_t)(N+1)*4);
    int*   tmp    = (int*)  alloc((size_t)N*4);
    int*   bsum   = (int*)  alloc(256*4);
    int2*  cew    = (int2*) alloc((size_t)E*8);
    float* dinv   = (float*)alloc((size_t)N*4);
    float* part   = (float*)alloc((size_t)2048*512*4);   // 4 MB
    float* part2  = (float*)alloc((size_t)64*512*4);     // 128 KB
    float* ab     = (float*)alloc(3*512*4);              // per-layer affine (A,B)
    unsigned short* Wt  = (unsigned short*)alloc(3*65536*2);
    unsigned short* hbA = (unsigned short*)alloc((size_t)N*256*2);
    unsigned short* hbB = (unsigned short*)alloc((size_t)N*256*2);
    unsigned short* ybf = (unsigned short*)alloc((size_t)N*256*2);
    unsigned short* zb  = (unsigned short*)alloc((size_t)N*256*2);

    // cnt region is rounded to 256B; ctr sits immediately after -> one memset covers both
    size_t cntRound = (((size_t)N*4 + 255)/256)*256;
    (void)hipMemsetAsync(cnt, 0, cntRound + 256, stream);

    const int* srcA = ei;
    const int* dstA = ei + E;
    int gE = (E+255)/256, gN = (N+255)/256;
    int n4 = N*64;
    int nbCvt = (n4+255)/256;
    k_hist_cvt<<<gE + nbCvt, 256, 0, stream>>>(dstA, cnt, E, gE, (const float4*)x, (ushort4*)hbA, n4);
    int nb = (N+1023)/1024;
    k_scan1<<<nb,1024,0,stream>>>(cnt, tmp, bsum, dinv, N);
    int padBlocks = (Bg*(512-G)*192 + 255)/256;
    k_scan3_misc<<<gN + 768 + padBlocks, 256, 0, stream>>>(tmp, bsum, rowptr, N, gN, nb,
                                                           Wp[0], Wp[1], Wp[2], Wt, (float4*)out, G);
    k_fill<<<gE,256,0,stream>>>(srcA, dstA, rowptr, cnt, dinv, cew, E);

    unsigned short* hin  = hbA;
    unsigned short* hout = hbB;
    dim3 ggrid((N+127)/128, 2);
    float invN = 1.0f / (float)N;
    for(int l=0; l<3; ++l){
        float* lab = ab + l*512;
        k_gemm<<<ggrid,256,0,stream>>>((const uint4*)hin, (const uint4*)(Wt + (size_t)l*65536), ybf, N);
        k_aggregate<<<2048,256,0,stream>>>((const uint4*)ybf, rowptr, cew, dinv, (uint4*)zb, part, N);
        k_red<<<64,256,0,stream>>>(part, part2, gam[l], bet[l], lab, invN, ctr + l);
        k_bnrelu<<<(n4+255)/256,256,0,stream>>>((const ushort4*)zb, lab,
                                                (l<2) ? (ushort4*)hout : (ushort4*)nullptr,
                                                (float4*)out, l, n4, G);
        unsigned short* t = hin; hin = hout; hout = t;
    }
}

// Round 14
// 419.984 us; speedup vs baseline: 1.0567x; 1.0429x over previous
//
#include <hip/hip_runtime.h>

typedef short bf16x8 __attribute__((ext_vector_type(8)));
typedef float f32x4 __attribute__((ext_vector_type(4)));

__device__ inline float bf2f(unsigned short s){ union{unsigned u; float f;} x; x.u=((unsigned)s)<<16; return x.f; }
__device__ inline unsigned short f2bf(float f){ union{float f; unsigned u;} x; x.f=f; unsigned r = x.u + 0x7fff + ((x.u>>16)&1u); return (unsigned short)(r>>16); }

// nt-store of a float4 via native ext-vector type (HIP_vector_type is rejected by the builtin)
__device__ inline void nt_store4(float4 v, float4* p){
    f32x4 t; t[0]=v.x; t[1]=v.y; t[2]=v.z; t[3]=v.w;
    __builtin_nontemporal_store(t, (f32x4*)p);
}

// async global->LDS, 16B per lane. ldsbase must be WAVE-UNIFORM; HW adds lane*16.
__device__ inline void gload16(const void* g, void* ldsbase){
    __builtin_amdgcn_global_load_lds((const __attribute__((address_space(1))) unsigned int*)g,
                                     (__attribute__((address_space(3))) unsigned int*)ldsbase, 16, 0, 0);
}

// ---------------- setup: hist | x->bf16 cvt (independent block ranges) ----------------
__global__ void k_hist_cvt(const int* __restrict__ dstA, int* __restrict__ cnt, int E, int histBlocks,
                           const float4* __restrict__ x4, ushort4* __restrict__ hb, int n4){
    int b = blockIdx.x;
    if(b < histBlocks){
        int e = b*256 + threadIdx.x;
        if(e < E) atomicAdd(&cnt[dstA[e]], 1);
    } else {
        int i = (b - histBlocks)*256 + threadIdx.x;
        if(i < n4){
            float4 v = x4[i];
            hb[i] = make_ushort4(f2bf(v.x), f2bf(v.y), f2bf(v.z), f2bf(v.w));
        }
    }
}

// scan1 also emits dinv = rsqrt(cnt+1)
__global__ void k_scan1(const int* __restrict__ cnt, int* __restrict__ tmp, int* __restrict__ bsum,
                        float* __restrict__ dinv, int n){
    __shared__ int s[1024];
    int i = blockIdx.x*1024 + threadIdx.x;
    int v = (i < n) ? cnt[i] : 0;
    if(i < n) dinv[i] = rsqrtf((float)(v + 1));
    s[threadIdx.x] = v; __syncthreads();
    for(int off=1; off<1024; off<<=1){
        int t = (threadIdx.x >= off) ? s[threadIdx.x-off] : 0;
        __syncthreads();
        s[threadIdx.x] += t;
        __syncthreads();
    }
    if(i < n) tmp[i] = s[threadIdx.x];
    if(threadIdx.x == 1023) bsum[blockIdx.x] = s[1023];
}

// scan3 (with in-block wave-scan of bsum) | W transpose | pad zeroing
__global__ void k_scan3_misc(const int* __restrict__ tmp, const int* __restrict__ bsum, int* __restrict__ rowptr,
                             int n, int gN, int nbScan,
                             const float* __restrict__ W0, const float* __restrict__ W1, const float* __restrict__ W2,
                             unsigned short* __restrict__ Wt, float4* __restrict__ out4, int G){
    int b = blockIdx.x;
    if(b < gN){
        __shared__ int pfx[64];
        if(threadIdx.x < 64){
            int v = ((int)threadIdx.x < nbScan) ? bsum[threadIdx.x] : 0;
            #pragma unroll
            for(int off=1; off<64; off<<=1){
                int t = __shfl_up(v, off, 64);
                if((int)threadIdx.x >= off) v += t;
            }
            pfx[threadIdx.x] = v;   // inclusive prefix
        }
        __syncthreads();
        int i = b*256 + threadIdx.x;
        if(i < n){
            int blk = i >> 10;
            int p = (blk == 0) ? 0 : pfx[blk-1];   // exclusive prefix
            rowptr[i+1] = tmp[i] + p;
            if(i == 0) rowptr[0] = 0;
        }
    } else if(b < gN + 768){
        int idx = (b - gN)*256 + threadIdx.x;
        int l = idx >> 16, rem = idx & 65535;
        int k = rem >> 8, nn = rem & 255;
        const float* W = (l==0) ? W0 : ((l==1) ? W1 : W2);
        Wt[l*65536 + nn*256 + k] = f2bf(W[k*256 + nn]);
    } else {
        int i = (b - gN - 768)*256 + threadIdx.x;
        int rowsPad = 512 - G;
        int per = rowsPad * 192;
        int total = 100 * per;
        if(i < total){
            int g = i / per; int rem = i - g*per;
            int r = rem / 192, c = rem - r*192;
            nt_store4(make_float4(0.f,0.f,0.f,0.f), &out4[((size_t)(g*512 + G + r))*192 + c]);
        }
    }
}

// fill via count-down on cnt (slot order within a row is irrelevant); writes (col, weight) pairs
__global__ void k_fill(const int* __restrict__ srcA, const int* __restrict__ dstA,
                       const int* __restrict__ rowptr, int* __restrict__ cnt,
                       const float* __restrict__ dinv, int2* __restrict__ cew, int E){
    int e = blockIdx.x*256 + threadIdx.x;
    if(e < E){
        int d = dstA[e], s = srcA[e];
        int slot = atomicSub(&cnt[d], 1) - 1;
        int j = rowptr[d] + slot;
        cew[j] = make_int2(s, __float_as_int(dinv[s]));
    }
}

// ---------------- GEMM: y[N,256] = hb[N,256] @ W[256,256]  (bf16 in, bf16 out) ----------------
// 128x128 tile, grid (ceil(N/128), 2) — proven version.
__global__ __launch_bounds__(256) void k_gemm(const uint4* __restrict__ A4,
                                              const uint4* __restrict__ B4,
                                              unsigned short* __restrict__ Y, int M){
    __shared__ uint4 smA[1024];   // 128 rows x 64 bf16
    __shared__ uint4 smB[1024];
    const int tid  = threadIdx.x;
    const int lane = tid & 63;
    const int w    = tid >> 6;
    const int wr   = w >> 1, wc = w & 1;
    const int r15  = lane & 15, hi = lane >> 4;
    const int rsub = lane >> 3, ch = lane & 7;
    const int rowBase = blockIdx.x * 128;
    const int colBase = blockIdx.y * 128;

    f32x4 acc[4][4] = {};
    char* pA = (char*)smA;
    char* pB = (char*)smB;

    for(int kt=0; kt<4; ++kt){
        const int kc0 = kt*8;
        #pragma unroll
        for(int i=0;i<4;++i){
            int row  = i*32 + w*8 + rsub;           // LDS row this lane covers
            int gch  = kc0 + (ch ^ (row & 7));      // pre-swizzled source chunk
            char* la = pA + i*4096 + w*1024;        // wave-uniform base; HW adds lane*16
            char* lb = pB + i*4096 + w*1024;
            int grow = rowBase + row;
            if(grow < M) gload16(&A4[(size_t)grow*32 + gch], la);
            gload16(&B4[(size_t)(colBase + row)*32 + gch], lb);
        }
        __syncthreads();
        #pragma unroll
        for(int kk=0; kk<2; ++kk){
            const int kbyte = kk*64 + hi*16;
            bf16x8 fa[4], fb[4];
            #pragma unroll
            for(int m=0;m<4;++m){
                int lrow = wr*64 + m*16 + r15;
                fa[m] = *(const bf16x8*)(pA + (lrow<<7) + (kbyte ^ ((lrow&7)<<4)));
            }
            #pragma unroll
            for(int nn=0;nn<4;++nn){
                int lcol = wc*64 + nn*16 + r15;
                fb[nn] = *(const bf16x8*)(pB + (lcol<<7) + (kbyte ^ ((lcol&7)<<4)));
            }
            #pragma unroll
            for(int m=0;m<4;++m)
                #pragma unroll
                for(int nn=0;nn<4;++nn)
                    acc[m][nn] = __builtin_amdgcn_mfma_f32_16x16x32_bf16(fa[m], fb[nn], acc[m][nn], 0,0,0);
        }
        __syncthreads();
    }
    #pragma unroll
    for(int m=0;m<4;++m){
        int growb = rowBase + wr*64 + m*16 + hi*4;
        #pragma unroll
        for(int nn=0;nn<4;++nn){
            int gcol = colBase + wc*64 + nn*16 + r15;
            #pragma unroll
            for(int r=0;r<4;++r){
                int grow = growb + r;
                if(grow < M) Y[(size_t)grow*256 + gcol] = f2bf(acc[m][nn][r]);
            }
        }
    }
}

// ---------------- aggregation + fused BN partial stats; split-lane dual-row gathers (4 dual-streams) ----------------
// lanes 0-31 gather even edges (16B/lane), lanes 32-63 odd edges; __shfl(lane^32) combines.
__global__ __launch_bounds__(256) void k_aggregate(const uint4* __restrict__ yb4,
                                                   const int* __restrict__ rowptr,
                                                   const int2* __restrict__ cew,
                                                   const float* __restrict__ dinv,
                                                   uint4* __restrict__ zb4,
                                                   float* __restrict__ part, int n){
    int lane = threadIdx.x & 63;
    int w    = threadIdx.x >> 6;
    int half = lane >> 5;          // 0: even edges, 1: odd edges
    int c    = lane & 31;          // 16B chunk index within a row
    float s[8] = {0,0,0,0,0,0,0,0};
    float q[8] = {0,0,0,0,0,0,0,0};

    for(int wid = blockIdx.x*4 + w; wid < n; wid += 2048*4){
        float di = dinv[wid];
        float acc[4][8];
        // self-loop: only half 0 accumulates it (half 1 gets weight 0)
        {
            uint4 d = yb4[(size_t)wid*32 + c];
            float ws = half ? 0.f : di;
            const unsigned short* p = (const unsigned short*)&d;
            #pragma unroll
            for(int k=0;k<8;++k) acc[0][k] = ws*bf2f(p[k]);
            #pragma unroll
            for(int k=0;k<8;++k){ acc[1][k]=0.f; acc[2][k]=0.f; acc[3][k]=0.f; }
        }
        int j = rowptr[wid], end = rowptr[wid+1];
        for(; j+7 < end; j += 8){
            #pragma unroll
            for(int u=0;u<4;++u){
                int2 e = cew[j + 2*u + half];
                float wt = __int_as_float(e.y);
                uint4 d = yb4[(size_t)e.x*32 + c];
                const unsigned short* p = (const unsigned short*)&d;
                #pragma unroll
                for(int k=0;k<8;++k) acc[u][k] += wt*bf2f(p[k]);
            }
        }
        for(; j+1 < end; j += 2){
            int2 e = cew[j + half];
            float wt = __int_as_float(e.y);
            uint4 d = yb4[(size_t)e.x*32 + c];
            const unsigned short* p = (const unsigned short*)&d;
            #pragma unroll
            for(int k=0;k<8;++k) acc[0][k] += wt*bf2f(p[k]);
        }
        if(j < end){
            int2 e = cew[j];
            float wt = half ? 0.f : __int_as_float(e.y);
            uint4 d = yb4[(size_t)e.x*32 + c];
            const unsigned short* p = (const unsigned short*)&d;
            #pragma unroll
            for(int k=0;k<8;++k) acc[0][k] += wt*bf2f(p[k]);
        }
        // merge 4 streams, then merge the two half-waves
        float o[8];
        #pragma unroll
        for(int k=0;k<8;++k){
            float v = (acc[0][k]+acc[1][k]) + (acc[2][k]+acc[3][k]);
            v += __shfl(v, lane ^ 32);
            o[k] = di * v;
        }
        if(half == 0){
            uint4 z;
            z.x = (unsigned)f2bf(o[0]) | ((unsigned)f2bf(o[1])<<16);
            z.y = (unsigned)f2bf(o[2]) | ((unsigned)f2bf(o[3])<<16);
            z.z = (unsigned)f2bf(o[4]) | ((unsigned)f2bf(o[5])<<16);
            z.w = (unsigned)f2bf(o[6]) | ((unsigned)f2bf(o[7])<<16);
            zb4[(size_t)wid*32 + c] = z;
            #pragma unroll
            for(int k=0;k<8;++k){ s[k] += o[k]; q[k] += o[k]*o[k]; }
        }
    }
    __shared__ float red[4][32][16];
    if(half == 0){
        #pragma unroll
        for(int k=0;k<8;++k){ red[w][c][k] = s[k]; red[w][c][8+k] = q[k]; }
    }
    __syncthreads();
    int t = threadIdx.x;  // feature t: chunk t>>3, elem t&7
    float vs = red[0][t>>3][t&7] + red[1][t>>3][t&7] + red[2][t>>3][t&7] + red[3][t>>3][t&7];
    float vq = red[0][t>>3][8+(t&7)] + red[1][t>>3][8+(t&7)] + red[2][t>>3][8+(t&7)] + red[3][t>>3][8+(t&7)];
    part[(size_t)blockIdx.x*512 + t]       = vs;
    part[(size_t)blockIdx.x*512 + 256 + t] = vq;
}

// reduce 2048 block-partials -> 64
__global__ __launch_bounds__(256) void k_red1(const float* __restrict__ part, float* __restrict__ part2){
    int c = threadIdx.x;
    int b = blockIdx.x;   // 0..63
    float s = 0.f, q = 0.f;
    for(int j = b*32; j < b*32 + 32; ++j){
        s += part[(size_t)j*512 + c];
        q += part[(size_t)j*512 + 256 + c];
    }
    part2[(size_t)b*512 + c]       = s;
    part2[(size_t)b*512 + 256 + c] = q;
}

// reduce 64 -> final; fold gamma/beta into per-feature affine (A, B)
__global__ __launch_bounds__(256) void k_red2(const float* __restrict__ part2,
                                              const float* __restrict__ gamma, const float* __restrict__ beta,
                                              float* __restrict__ ab, float invN){
    int c = threadIdx.x;
    float s = 0.f, q = 0.f;
    for(int j=0;j<64;++j){
        s += part2[(size_t)j*512 + c];
        q += part2[(size_t)j*512 + 256 + c];
    }
    float mu  = s*invN;
    float var = q*invN - mu*mu;
    float A   = gamma[c]*rsqrtf(var + 1e-5f);
    ab[c]       = A;
    ab[256 + c] = beta[c] - mu*A;
}

// ---------------- BN affine + ReLU + next-layer bf16 + dense-batch output write (nt) ----------------
__global__ __launch_bounds__(256) void k_bnrelu(const ushort4* __restrict__ zb, const float* __restrict__ ab,
                                                ushort4* __restrict__ hb_out, float4* __restrict__ out4,
                                                int layer, int n4, int G){
    int idx = blockIdx.x*256 + threadIdx.x;
    if(idx >= n4) return;
    int node = idx >> 6, q = idx & 63;
    ushort4 v = zb[idx];
    float4 A  = ((const float4*)ab)[q];
    float4 Bv = ((const float4*)(ab + 256))[q];
    float4 r;
    r.x = fmaxf(fmaf(bf2f(v.x), A.x, Bv.x), 0.f);
    r.y = fmaxf(fmaf(bf2f(v.y), A.y, Bv.y), 0.f);
    r.z = fmaxf(fmaf(bf2f(v.z), A.z, Bv.z), 0.f);
    r.w = fmaxf(fmaf(bf2f(v.w), A.w, Bv.w), 0.f);
    if(hb_out) hb_out[idx] = make_ushort4(f2bf(r.x), f2bf(r.y), f2bf(r.z), f2bf(r.w));
    int g2 = node / G;
    int p  = node - g2*G;
    nt_store4(r, &out4[((size_t)(g2*512 + p))*192 + layer*64 + q]);
}

extern "C" void kernel_launch(void* const* d_in, const int* in_sizes, int n_in,
                              void* d_out, int out_size, void* d_ws, size_t ws_size,
                              hipStream_t stream){
    const int F = 256;
    const int N = in_sizes[0] / F;      // 50000
    const int E = in_sizes[1] / 2;      // 800000
    const int Bg = 100;
    const int G = N / Bg;               // 500

    const float* x  = (const float*)d_in[0];
    const int*   ei = (const int*)d_in[1];
    const float* Wp[3]  = {(const float*)d_in[4],  (const float*)d_in[8],  (const float*)d_in[12]};
    const float* gam[3] = {(const float*)d_in[6],  (const float*)d_in[10], (const float*)d_in[14]};
    const float* bet[3] = {(const float*)d_in[7],  (const float*)d_in[11], (const float*)d_in[15]};
    float* out = (float*)d_out;

    char* wp = (char*)d_ws;
    auto alloc = [&](size_t b)->char*{ char* p = wp; wp += ((b + 255)/256)*256; return p; };
    int*   cnt    = (int*)  alloc((size_t)N*4);
    int*   rowptr = (int*)  alloc((size_t)(N+1)*4);
    int*   tmp    = (int*)  alloc((size_t)N*4);
    int*   bsum   = (int*)  alloc(256*4);
    int2*  cew    = (int2*) alloc((size_t)E*8);
    float* dinv   = (float*)alloc((size_t)N*4);
    float* part   = (float*)alloc((size_t)2048*512*4);   // 4 MB
    float* part2  = (float*)alloc((size_t)64*512*4);     // 128 KB
    float* ab     = (float*)alloc(3*512*4);              // per-layer affine (A,B)
    unsigned short* Wt  = (unsigned short*)alloc(3*65536*2);
    unsigned short* hbA = (unsigned short*)alloc((size_t)N*256*2);
    unsigned short* hbB = (unsigned short*)alloc((size_t)N*256*2);
    unsigned short* ybf = (unsigned short*)alloc((size_t)N*256*2);
    unsigned short* zb  = (unsigned short*)alloc((size_t)N*256*2);

    (void)hipMemsetAsync(cnt, 0, (size_t)N*4, stream);

    const int* srcA = ei;
    const int* dstA = ei + E;
    int gE = (E+255)/256, gN = (N+255)/256;
    int n4 = N*64;
    int nbCvt = (n4+255)/256;
    k_hist_cvt<<<gE + nbCvt, 256, 0, stream>>>(dstA, cnt, E, gE, (const float4*)x, (ushort4*)hbA, n4);
    int nb = (N+1023)/1024;
    k_scan1<<<nb,1024,0,stream>>>(cnt, tmp, bsum, dinv, N);
    int padBlocks = (Bg*(512-G)*192 + 255)/256;
    k_scan3_misc<<<gN + 768 + padBlocks, 256, 0, stream>>>(tmp, bsum, rowptr, N, gN, nb,
                                                           Wp[0], Wp[1], Wp[2], Wt, (float4*)out, G);
    k_fill<<<gE,256,0,stream>>>(srcA, dstA, rowptr, cnt, dinv, cew, E);

    unsigned short* hin  = hbA;
    unsigned short* hout = hbB;
    dim3 ggrid((N+127)/128, 2);
    float invN = 1.0f / (float)N;
    for(int l=0; l<3; ++l){
        float* lab = ab + l*512;
        k_gemm<<<ggrid,256,0,stream>>>((const uint4*)hin, (const uint4*)(Wt + (size_t)l*65536), ybf, N);
        k_aggregate<<<2048,256,0,stream>>>((const uint4*)ybf, rowptr, cew, dinv, (uint4*)zb, part, N);
        k_red1<<<64,256,0,stream>>>(part, part2);
        k_red2<<<1,256,0,stream>>>(part2, gam[l], bet[l], lab, invN);
        k_bnrelu<<<(n4+255)/256,256,0,stream>>>((const ushort4*)zb, lab,
                                                (l<2) ? (ushort4*)hout : (ushort4*)nullptr,
                                                (float4*)out, l, n4, G);
        unsigned short* t = hin; hin = hout; hout = t;
    }
}